// Round 3
// baseline (2530.036 us; speedup 1.0000x reference)
//
#include <hip/hip_runtime.h>
#include <math.h>

// ---------------------------------------------------------------------------
// VertexGNN on MI355X — round 18: bucket-grouped scatter + LDS aggregation.
// R15-R17 proved per-node scatter can't merge (100K active partial lines >>
// L2). Fix: scatter only to 764 bucket cursors (131 dst nodes each; 48KB of
// active lines -> full L2 merge; role = bucket&7 keeps writers on one XCD).
// Edge kernel: one block per bucket, LDS agg tile (131x68 f32, ds_add_f32),
// streamed nt write-out -> NO global agg atomics, NO agg memset, NO re-zero.
// Records are int2 (src | dloc<<20, packed bf16 ea) = 12.8MB streams.
// ---------------------------------------------------------------------------

typedef __attribute__((ext_vector_type(8))) short bfrag;   // 8 x bf16
typedef __attribute__((ext_vector_type(4))) float ffrag;   // 4 x f32
typedef __attribute__((ext_vector_type(4))) float f32x4;

#define WBUK 131          // dst nodes per bucket
#define MAGW 4196609267u  // ceil(2^39/131): d/131 = umulhi(d,MAGW)>>7, exact
#define LSTR 68           // lagg row stride (floats): 16B-aligned, bank-spread

template <int CTRL>
__device__ __forceinline__ float dpp_mov(float v) {
  return __int_as_float(
      __builtin_amdgcn_update_dpp(0, __float_as_int(v), CTRL, 0xF, 0xF, true));
}

__device__ __forceinline__ float rsum16(float v) {
  v += dpp_mov<0x128>(v);   // row_ror:8
  v += dpp_mov<0x124>(v);   // row_ror:4
  v += dpp_mov<0x122>(v);   // row_ror:2
  v += dpp_mov<0x121>(v);   // row_ror:1
  return v;
}

__device__ __forceinline__ float wave_sum64(float v) {
  v = rsum16(v);
  v += __shfl_xor(v, 16, 64);
  v += __shfl_xor(v, 32, 64);
  return v;
}

// LN with independent E[x], E[x^2] reductions (chains overlap)
__device__ __forceinline__ float ln_apply(float t, float g, float b) {
  float s1 = wave_sum64(t);
  float s2 = wave_sum64(t * t);
  float mu = s1 * 0.015625f;
  float var = fmaf(-mu, mu, s2 * 0.015625f);
  return (t - mu) * rsqrtf(var + 1e-5f) * g + b;
}

// A&S 7.1.27: erf(x) ~= 1 - 1/poly^4, |err|<=5e-4; single v_rcp.
__device__ __forceinline__ float erf_fast(float x) {
  float ax = fabsf(x);
  float p = fmaf(fmaf(fmaf(fmaf(0.078108f, ax, 0.000972f), ax, 0.230389f),
                      ax, 0.278393f), ax, 1.0f);
  p = p * p;
  p = p * p;
  float r = __builtin_amdgcn_rcpf(p);
  return copysignf(1.0f - r, x);
}

__device__ __forceinline__ float gelu_exact(float v) {
  float half = 0.5f * v;
  return fmaf(half, erf_fast(v * 0.70710678118654752440f), half);
}

__device__ __forceinline__ float lane_bcast(float v, int k) {
  return __uint_as_float(__builtin_amdgcn_readlane(__float_as_uint(v), k));
}

// float -> bf16 (RNE)
__device__ __forceinline__ short f2bf(float f) {
  union { float f; unsigned u; } v; v.f = f;
  unsigned r = v.u + 0x7fffu + ((v.u >> 16) & 1u);
  return (short)(r >> 16);
}

// ---------------- init stage 1: prep_w | hist -------------------------------
__global__ __launch_bounds__(256) void k_init1(
    const float* __restrict__ conv_w, ushort* __restrict__ wt,
    const int* __restrict__ ei, int* __restrict__ csr,
    int ne, int oHist) {
  const int bid = blockIdx.x;
  const int tid = threadIdx.x;
  if (bid < oHist) {  // prep_w: 3*64*96 = 18432 elems, 72 blocks
    const int i = bid * 256 + tid;
    const int k = i % 96, f = (i / 96) % 64, l = i / (96 * 64);
    const float v = (k < 66) ? conv_w[(size_t)l * 66 * 64 + k * 64 + f] : 0.0f;
    wt[i] = (ushort)f2bf(v);
    return;
  }
  const int i = (bid - oHist) * 256 + tid;   // degree histogram
  if (i < ne) atomicAdd(&csr[__builtin_nontemporal_load(ei + ne + i)], 1);
}

// Single-block exclusive scan. Adds: csr[n] = NE sentinel, bcur[b] = csr[b*W].
__global__ __launch_bounds__(1024) void k_scan_fast(int* __restrict__ buf,
                                                    int* __restrict__ bcur,
                                                    int n, int nbuck) {
  __shared__ int wsum[16];
  const int tid = threadIdx.x, lane = tid & 63, w = tid >> 6;
  const int chunk = (((n + 1023) / 1024) + 3) & ~3;   // multiple of 4
  const int a = min(tid * chunk, n), b = min(a + chunk, n);
  const bool full = (a + chunk <= n);
  int s = 0;
  if (full) {
    const int4* p4 = (const int4*)(buf + a);
#pragma unroll 4
    for (int i = 0; i < chunk / 4; i++) {
      int4 v = p4[i];
      s += v.x + v.y + v.z + v.w;
    }
  } else {
    for (int i = a; i < b; i++) s += buf[i];
  }
  int inc = s;
#pragma unroll
  for (int sh = 1; sh < 64; sh <<= 1) {
    int t = __shfl_up(inc, sh, 64);
    if (lane >= sh) inc += t;
  }
  if (lane == 63) wsum[w] = inc;
  __syncthreads();
  int wb = 0;
  for (int j = 0; j < w; j++) wb += wsum[j];
  int excl = wb + inc - s;
  if (full) {
    int4* p4 = (int4*)(buf + a);
#pragma unroll 4
    for (int i = 0; i < chunk / 4; i++) {
      int4 v = p4[i];
      int4 o;
      o.x = excl; excl += v.x;
      o.y = excl; excl += v.y;
      o.z = excl; excl += v.z;
      o.w = excl; excl += v.w;
      p4[i] = o;
    }
  } else {
    for (int i = a; i < b; i++) { int v = buf[i]; buf[i] = excl; excl += v; }
  }
  __syncthreads();
  if (tid == 0) {   // sentinel: csr[n] = total
    int tot = 0;
#pragma unroll
    for (int j = 0; j < 16; j++) tot += wsum[j];
    buf[n] = tot;
  }
  // bucket cursors (scan writes visible after barrier above)
  for (int bq = tid; bq < nbuck; bq += 1024) bcur[bq] = buf[min(bq * WBUK, n)];
}

// ---------------- init stage 2: bucket scatter | embed ----------------------
// Per 32-block group: blocks 0..23 scatter (role = bid&7 ~ XCD; claims edges
// whose bucket&7 == role -> each bucket written by ONE XCD, 764 active lines
// merge in L2), blocks 24..31 embed.
__global__ __launch_bounds__(256) void k_combo(
    const int* __restrict__ ei, const float* __restrict__ ea,
    int* __restrict__ bcur, int2* __restrict__ edata,
    const float* __restrict__ x,
    const float* __restrict__ w1, const float* __restrict__ b1,
    const float* __restrict__ g1, const float* __restrict__ be1,
    const float* __restrict__ w2, const float* __restrict__ b2,
    const float* __restrict__ g2, const float* __restrict__ be2,
    float* __restrict__ h, ushort* __restrict__ hb,
    int n_nodes, int ne, int nOrd, int embWaves) {
  const int bid = blockIdx.x;
  const int tid = threadIdx.x;
  const int sub = bid & 31;
  if (sub < 24) {  // ---- scatter (bucket-partitioned by role) ----
    const int role = bid & 7;
    const int ord = (bid >> 5) * 3 + (sub >> 3);     // ordinal within role
    const int lo = (int)((long long)ord * ne / nOrd);
    const int hi = (int)((long long)(ord + 1) * ne / nOrd);
    for (int i = lo + tid; i < hi; i += 256) {
      const int d = __builtin_nontemporal_load(ei + ne + i);   // nt: stream
      const unsigned bq = __umulhi((unsigned)d, MAGW) >> 7;    // d / 131
      if ((int)(bq & 7u) == role) {
        const int s = __builtin_nontemporal_load(ei + i);      // nt: stream
        const unsigned long long eau =
            __builtin_nontemporal_load((const unsigned long long*)ea + i);
        const float e0 = __uint_as_float((unsigned)eau);
        const float e1 = __uint_as_float((unsigned)(eau >> 32));
        const unsigned pk = (unsigned)(ushort)f2bf(e0) |
                            ((unsigned)(ushort)f2bf(e1) << 16);
        const int dloc = d - (int)bq * WBUK;
        const int pos = atomicAdd(&bcur[bq], 1);
        edata[pos] = make_int2(s | (dloc << 20), (int)pk);  // cached: merges
      }
    }
    return;
  }
  // ---- node embedding ----
  const int lane = tid & 63;
  const int eblk = (bid >> 5) * 8 + (sub - 24);
  const int wid = (eblk * 256 + tid) >> 6;
  const int nw = embWaves;
  float wc[64];
#pragma unroll
  for (int k = 0; k < 64; k++) wc[k] = w2[k * 64 + lane];
  const float w1a = w1[lane], w1b = w1[64 + lane];
  const float vb1 = b1[lane], vg1 = g1[lane], vbe1 = be1[lane];
  const float vb2 = b2[lane], vg2 = g2[lane], vbe2 = be2[lane];
  for (int n = wid; n < n_nodes; n += nw) {
    const float x0 = x[2 * n], x1 = x[2 * n + 1];
    float t = fmaf(x0, w1a, fmaf(x1, w1b, vb1));
    t = gelu_exact(ln_apply(t, vg1, vbe1));
    float a0 = vb2, a1 = 0.f, a2 = 0.f, a3 = 0.f;
#pragma unroll
    for (int k = 0; k < 64; k += 4) {
      a0 = fmaf(lane_bcast(t, k + 0), wc[k + 0], a0);
      a1 = fmaf(lane_bcast(t, k + 1), wc[k + 1], a1);
      a2 = fmaf(lane_bcast(t, k + 2), wc[k + 2], a2);
      a3 = fmaf(lane_bcast(t, k + 3), wc[k + 3], a3);
    }
    float acc = (a0 + a1) + (a2 + a3);
    acc = gelu_exact(ln_apply(acc, vg2, vbe2));
    __builtin_nontemporal_store(acc, h + (size_t)n * 64 + lane);   // nt: stream
    __builtin_nontemporal_store((ushort)f2bf(acc),
                                hb + (size_t)n * 64 + lane);       // nt: stream
  }
}

// ---------------- edge-message kernel: one block per bucket -----------------
// MFMA message MLP + LN + GELU as before; aggregation into LDS tile via
// ds_add_f32, then streamed nt write-out. No global atomics, no agg zeroing.
__global__ __launch_bounds__(256, 3) void k_edge_lds(
    const ushort* __restrict__ hb_in, float* __restrict__ agg,
    const int2* __restrict__ edata, const int* __restrict__ csr,
    const ushort* __restrict__ wt,
    const float* __restrict__ bias, const float* __restrict__ mg,
    const float* __restrict__ mb, int nn) {
  __shared__ __align__(16) ushort lwt[64 * 96];       // 12 KB: B^T tiles
  __shared__ __align__(16) float lagg[WBUK * LSTR];   // 35.6 KB agg tile
  {
    const uint4* s = (const uint4*)wt;
    uint4* d = (uint4*)lwt;
    for (int i = threadIdx.x; i < 768; i += 256) d[i] = s[i];
    f32x4* z = (f32x4*)lagg;
    const f32x4 zz = {0.f, 0.f, 0.f, 0.f};
    for (int i = threadIdx.x; i < (WBUK * LSTR) / 4; i += 256) z[i] = zz;
  }
  const int bq = blockIdx.x;
  const int nlo = bq * WBUK;
  const int nhi = min(nlo + WBUK, nn);
  const int lo = csr[nlo], hi = csr[nhi];
  __syncthreads();

  const int lane = threadIdx.x & 63;
  const int wv = threadIdx.x >> 6;
  const int grp = lane >> 4, col = lane & 15;

  float vb[4], vg[4], vbb[4];
#pragma unroll
  for (int t = 0; t < 4; t++) {
    const int f = t * 16 + col;
    vb[t] = bias[f]; vg[t] = mg[f]; vbb[t] = mb[f];
  }

  const int nch = (hi - lo + 15) >> 4;
  int c = wv;
  if (c < nch) {
    int slot = min(lo + 16 * c + col, hi - 1);
    int2 e = edata[slot];
    const ushort* hp0 = hb_in + (size_t)(e.x & 0xFFFFF) * 64 + grp * 8;
    bfrag A0 = *(const bfrag*)(hp0);
    bfrag A1 = *(const bfrag*)(hp0 + 32);

    for (;;) {
      const int rem = min(16, hi - lo - 16 * c);
      const int cn = c + 4;
      const bool more = cn < nch;
      const int nslot = more ? min(lo + 16 * cn + col, hi - 1) : slot;
      const int2 en = edata[nslot];   // prefetch next chunk payload

      bfrag A2 = {0, 0, 0, 0, 0, 0, 0, 0};
      if (grp == 0) {
        A2[0] = (short)(e.y & 0xffff);
        A2[1] = (short)((unsigned)e.y >> 16);
      }

      ffrag acc[4];
#pragma unroll
      for (int t = 0; t < 4; t++) { ffrag cc = {vb[t], vb[t], vb[t], vb[t]}; acc[t] = cc; }
#pragma unroll
      for (int t = 0; t < 4; t++) {
        const bfrag B = *(const bfrag*)(lwt + (t * 16 + col) * 96 + grp * 8);
        acc[t] = __builtin_amdgcn_mfma_f32_16x16x32_bf16(A0, B, acc[t], 0, 0, 0);
      }
#pragma unroll
      for (int t = 0; t < 4; t++) {
        const bfrag B = *(const bfrag*)(lwt + (t * 16 + col) * 96 + 32 + grp * 8);
        acc[t] = __builtin_amdgcn_mfma_f32_16x16x32_bf16(A1, B, acc[t], 0, 0, 0);
      }
#pragma unroll
      for (int t = 0; t < 4; t++) {
        const bfrag B = *(const bfrag*)(lwt + (t * 16 + col) * 96 + 64 + grp * 8);
        acc[t] = __builtin_amdgcn_mfma_f32_16x16x32_bf16(A2, B, acc[t], 0, 0, 0);
      }

      // prefetch next chunk's gather so it flies during the epilogue
      const ushort* hq = hb_in + (size_t)(en.x & 0xFFFFF) * 64 + grp * 8;
      const bfrag N0 = *(const bfrag*)(hq);
      const bfrag N1 = *(const bfrag*)(hq + 32);

      // ---- per-edge LN stats via E[x] / E[x^2] (edge row m = grp*4+r) ----
      float sx[4], sq[4];
#pragma unroll
      for (int r = 0; r < 4; r++) {
        float s = (acc[0][r] + acc[1][r]) + (acc[2][r] + acc[3][r]);
        float q = fmaf(acc[0][r], acc[0][r], fmaf(acc[1][r], acc[1][r],
                  fmaf(acc[2][r], acc[2][r], acc[3][r] * acc[3][r])));
        sx[r] = s; sq[r] = q;
      }
#pragma unroll
      for (int r = 0; r < 4; r++) sx[r] = rsum16(sx[r]);
#pragma unroll
      for (int r = 0; r < 4; r++) sq[r] = rsum16(sq[r]);
      float iv[4], mi[4];
#pragma unroll
      for (int r = 0; r < 4; r++) {
        const float mu = sx[r] * 0.015625f;
        const float var = fmaf(-mu, mu, sq[r] * 0.015625f);
        iv[r] = rsqrtf(var + 1e-5f);
        mi[r] = -mu * iv[r];
      }

      // ---- LN-apply + GELU, in place ----
#pragma unroll
      for (int t = 0; t < 4; t++) {
#pragma unroll
        for (int r = 0; r < 4; r++) {
          const float z = fmaf(acc[t][r], iv[r], mi[r]);
          acc[t][r] = gelu_exact(fmaf(z, vg[t], vbb[t]));
        }
      }

      // ---- LDS aggregation: lagg[dloc(row)*LSTR + t*16 + col] += acc ----
      const int dloc = (int)(((unsigned)e.x) >> 20);
      int ad[4];
#pragma unroll
      for (int r = 0; r < 4; r++)
        ad[r] = __shfl(dloc, grp * 4 + r, 64) * LSTR;
#pragma unroll
      for (int r = 0; r < 4; r++) {
        const int row = grp * 4 + r;
        if (row < rem) {
#pragma unroll
          for (int t = 0; t < 4; t++)
            atomicAdd(&lagg[ad[r] + t * 16 + col], acc[t][r]);
        }
      }

      if (!more) break;
      c = cn; slot = nslot; e = en; A0 = N0; A1 = N1;
    }
  }
  __syncthreads();

  // ---- streamed write-out of the tile (fully overwrites agg rows) ----
  const int wbk = nhi - nlo;
  for (int u = threadIdx.x; u < wbk * 16; u += 256) {
    const int i = u >> 4, j = u & 15;
    const f32x4 v = *(const f32x4*)(lagg + i * LSTR + j * 4);
    __builtin_nontemporal_store(v, (f32x4*)(agg + ((size_t)(nlo + i) * 64 + j * 4)));
  }
}

// ---------------------- node update (in-place h) ----------------------------
__global__ void k_node_update(float* __restrict__ h, ushort* __restrict__ hb,
                              const float* __restrict__ agg, const int* __restrict__ csr,
                              const float* __restrict__ ng, const float* __restrict__ nb,
                              const float* __restrict__ og, const float* __restrict__ ob,
                              int n_nodes, int writeHb) {
  const int lane = threadIdx.x & 63;
  const int n = (blockIdx.x * blockDim.x + threadIdx.x) >> 6;
  if (n >= n_nodes) return;
  const int2 se = *(const int2*)(csr + n);   // (start, end) — csr pristine
  const float dg = fmaxf((float)(se.y - se.x), 1.0f);
  const float hv = h[(size_t)n * 64 + lane];
  const float a = agg[(size_t)n * 64 + lane] / dg + hv;
  const float c = ln_apply(a, ng[lane], nb[lane]);
  const float o = ln_apply(c, og[lane], ob[lane]);
  const float outv = hv + o;
  h[(size_t)n * 64 + lane] = outv;
  if (writeHb) hb[(size_t)n * 64 + lane] = (ushort)f2bf(outv);
}

// ------------------------------ pooling (segmented) -------------------------
__global__ void k_pool_seg(const float* __restrict__ h, const int* __restrict__ batch,
                           float* __restrict__ g, float* __restrict__ cnt,
                           int n_nodes, int chunk) {
  const int lane = threadIdx.x & 63;
  const int wid = (blockIdx.x * blockDim.x + threadIdx.x) >> 6;
  const int n0 = wid * chunk;
  if (n0 >= n_nodes) return;
  const int n1 = min(n0 + chunk, n_nodes);
  int cur = batch[n0], c = 0;
  float acc = 0.f;
  for (int n = n0; n < n1; n++) {
    const int b = batch[n];
    if (b != cur) {
      atomicAdd(&g[(size_t)cur * 64 + lane], acc);
      if (lane == 0) atomicAdd(&cnt[cur], (float)c);
      acc = 0.f; c = 0; cur = b;
    }
    acc += h[(size_t)n * 64 + lane];
    c++;
  }
  atomicAdd(&g[(size_t)cur * 64 + lane], acc);
  if (lane == 0) atomicAdd(&cnt[cur], (float)c);
}

// ------------------------------- head --------------------------------------
__global__ void k_head(const float* __restrict__ g, const float* __restrict__ cnt,
                       const float* __restrict__ w1, const float* __restrict__ b1,
                       const float* __restrict__ g1, const float* __restrict__ be1,
                       const float* __restrict__ w2, const float* __restrict__ b2,
                       const float* __restrict__ g2, const float* __restrict__ be2,
                       const float* __restrict__ w3, const float* __restrict__ b3,
                       float* __restrict__ out, int nb_) {
  const int lane = threadIdx.x & 63;
  const int row = (blockIdx.x * blockDim.x + threadIdx.x) >> 6;
  if (row >= nb_) return;
  const float c = fmaxf(cnt[row], 1.0f);
  const float gv = g[row * 64 + lane] / c;
  float a0 = b1[lane], a1 = 0.f, a2 = 0.f, a3 = 0.f;
#pragma unroll
  for (int k = 0; k < 64; k += 4) {
    a0 = fmaf(lane_bcast(gv, k + 0), w1[(k + 0) * 64 + lane], a0);
    a1 = fmaf(lane_bcast(gv, k + 1), w1[(k + 1) * 64 + lane], a1);
    a2 = fmaf(lane_bcast(gv, k + 2), w1[(k + 2) * 64 + lane], a2);
    a3 = fmaf(lane_bcast(gv, k + 3), w1[(k + 3) * 64 + lane], a3);
  }
  float t = (a0 + a1) + (a2 + a3);
  t = fmaxf(ln_apply(t, g1[lane], be1[lane]), 0.0f);

  const int j = lane & 31;
  float c0 = b2[j], c1 = 0.f, c2 = 0.f, c3 = 0.f;
#pragma unroll
  for (int k = 0; k < 64; k += 4) {
    c0 = fmaf(lane_bcast(t, k + 0), w2[(k + 0) * 32 + j], c0);
    c1 = fmaf(lane_bcast(t, k + 1), w2[(k + 1) * 32 + j], c1);
    c2 = fmaf(lane_bcast(t, k + 2), w2[(k + 2) * 32 + j], c2);
    c3 = fmaf(lane_bcast(t, k + 3), w2[(k + 3) * 32 + j], c3);
  }
  float t2 = (c0 + c1) + (c2 + c3);
  t2 = fmaxf(ln_apply(t2, g2[j], be2[j]), 0.0f);
  const float p = t2 * w3[j];
  const float s = wave_sum64(p) * 0.5f;
  if (lane == 0) out[row] = s + b3[0];
}

// ---------------------------------------------------------------------------
extern "C" void kernel_launch(void* const* d_in, const int* in_sizes, int n_in,
                              void* d_out, int out_size, void* d_ws, size_t ws_size,
                              hipStream_t stream) {
  const float* x      = (const float*)d_in[0];
  const float* ea     = (const float*)d_in[1];
  const float* ne_w1  = (const float*)d_in[2];
  const float* ne_b1  = (const float*)d_in[3];
  const float* ne_g1  = (const float*)d_in[4];
  const float* ne_be1 = (const float*)d_in[5];
  const float* ne_w2  = (const float*)d_in[6];
  const float* ne_b2  = (const float*)d_in[7];
  const float* ne_g2  = (const float*)d_in[8];
  const float* ne_be2 = (const float*)d_in[9];
  const float* conv_w = (const float*)d_in[10];
  const float* conv_b = (const float*)d_in[11];
  const float* conv_mg= (const float*)d_in[12];
  const float* conv_mb= (const float*)d_in[13];
  const float* conv_ng= (const float*)d_in[14];
  const float* conv_nb= (const float*)d_in[15];
  const float* out_ng = (const float*)d_in[16];
  const float* out_nb = (const float*)d_in[17];
  const float* m_w1   = (const float*)d_in[18];
  const float* m_b1   = (const float*)d_in[19];
  const float* m_g1   = (const float*)d_in[20];
  const float* m_be1  = (const float*)d_in[21];
  const float* m_w2   = (const float*)d_in[22];
  const float* m_b2   = (const float*)d_in[23];
  const float* m_g2   = (const float*)d_in[24];
  const float* m_be2  = (const float*)d_in[25];
  const float* m_w3   = (const float*)d_in[26];
  const float* m_b3   = (const float*)d_in[27];
  const int*   eidx   = (const int*)d_in[28];
  const int*   batch  = (const int*)d_in[29];
  float* outp = (float*)d_out;

  const int NN = in_sizes[29];
  const int NE = in_sizes[1] / 2;
  const int NB = out_size;
  const int NBUCK = (NN + WBUK - 1) / WBUK;            // 764 @ NN=100000

  // workspace
  char* wsb = (char*)d_ws;
  float*  h     = (float*)wsb;                           // NN*64 f32
  ushort* hb    = (ushort*)(h + (size_t)NN * 64);        // NN*64 bf16
  int2*   edata = (int2*)((char*)hb + (size_t)NN * 128); // NE int2 (8B)
  ushort* wt    = (ushort*)(edata + NE);                 // 3*64*96 bf16
  float*  agg   = (float*)(wt + 3 * 64 * 96);            // NN*64 f32 (no zero!)
  float*  gbuf  = agg + (size_t)NN * 64;                 // NB*64 f32  --+
  float*  cnt   = gbuf + (size_t)NB * 64;                // NB f32       | one
  int*    csr   = (int*)(cnt + NB);                      // (NN+1) int   | memset
  int*    bcur  = csr + (NN + 1);                        // NBUCK int  --+

  const dim3 blk(256);

  // zero gbuf + cnt + csr(+sentinel) + bcur in one contiguous memset
  const size_t zbytes = (char*)(bcur + NBUCK) - (char*)gbuf;
  hipMemsetAsync(gbuf, 0, zbytes, stream);

  // stage 1: prep(72) | hist
  const int nPrep = (3 * 64 * 96) / 256;              // 72
  const int nHist = (NE + 255) / 256;
  k_init1<<<nPrep + nHist, blk, 0, stream>>>(conv_w, wt, eidx, csr, NE, nPrep);

  k_scan_fast<<<1, 1024, 0, stream>>>(csr, bcur, NN, NBUCK);

  // stage 2: bucket scatter | embed, interleaved per 32-block group
  const int ngroups = 261;                            // 24 scat + 8 emb per group
  const int nOrd = ngroups * 3;                       // ordinals per role
  const int nEmb = ngroups * 8;
  k_combo<<<ngroups * 32, blk, 0, stream>>>(
      eidx, ea, bcur, edata, x,
      ne_w1, ne_b1, ne_g1, ne_be1, ne_w2, ne_b2, ne_g2, ne_be2,
      h, hb, NN, NE, nOrd, nEmb * 4);

  for (int l = 0; l < 3; l++) {
    k_edge_lds<<<NBUCK, blk, 0, stream>>>(
        hb, agg, edata, csr, wt + (size_t)l * 64 * 96,
        conv_b + l * 64, conv_mg + l * 64, conv_mb + l * 64, NN);
    k_node_update<<<(NN * 64 + 255) / 256, blk, 0, stream>>>(
        h, hb, agg, csr, conv_ng + l * 64, conv_nb + l * 64,
        out_ng + l * 64, out_nb + l * 64, NN, (l < 2) ? 1 : 0);
  }

  {
    const int chunk = 32;
    const int nwaves = (NN + chunk - 1) / chunk;
    const int nblocks = (nwaves * 64 + 255) / 256;
    k_pool_seg<<<nblocks, blk, 0, stream>>>(h, batch, gbuf, cnt, NN, chunk);
  }
  k_head<<<(NB + 3) / 4, blk, 0, stream>>>(gbuf, cnt, m_w1, m_b1, m_g1, m_be1,
                                           m_w2, m_b2, m_g2, m_be2, m_w3, m_b3,
                                           outp, NB);
}

// Round 4
// 862.913 us; speedup vs baseline: 2.9320x; 2.9320x over previous
//
#include <hip/hip_runtime.h>
#include <math.h>

// ---------------------------------------------------------------------------
// VertexGNN on MI355X — round 19 = R17 core + fused per-wave CSR layer kernel.
// R18 lesson: bucket cursors -> 2100-deep atomic chains (scatter 4.5x worse);
// revert to per-node cursors (proven 136us). New: k_layer replaces
// k_edge_packed + k_node_update. Each wave owns a contiguous NODE range (and
// thus a contiguous dst-sorted edge range, partition precomputed in the scan),
// accumulates each node's message sum in registers across 16-edge MFMA tiles,
// and finishes the node inline (mean, LN, LN, residual, h/hb store).
// Deletes: agg array, all agg atomics, agg memset + re-zero, 3 launches.
// hb is ping-ponged (gather source vs update race); h updated in place
// (owner-exclusive).
// ---------------------------------------------------------------------------

typedef __attribute__((ext_vector_type(8))) short bfrag;   // 8 x bf16
typedef __attribute__((ext_vector_type(4))) float ffrag;   // 4 x f32

#define NWV 16384   // waves in k_layer (4096 blocks x 4 waves)

template <int CTRL>
__device__ __forceinline__ float dpp_mov(float v) {
  return __int_as_float(
      __builtin_amdgcn_update_dpp(0, __float_as_int(v), CTRL, 0xF, 0xF, true));
}

__device__ __forceinline__ float rsum16(float v) {
  v += dpp_mov<0x128>(v);   // row_ror:8
  v += dpp_mov<0x124>(v);   // row_ror:4
  v += dpp_mov<0x122>(v);   // row_ror:2
  v += dpp_mov<0x121>(v);   // row_ror:1
  return v;
}

__device__ __forceinline__ float wave_sum64(float v) {
  v = rsum16(v);
  v += __shfl_xor(v, 16, 64);
  v += __shfl_xor(v, 32, 64);
  return v;
}

// LN with independent E[x], E[x^2] reductions (chains overlap)
__device__ __forceinline__ float ln_apply(float t, float g, float b) {
  float s1 = wave_sum64(t);
  float s2 = wave_sum64(t * t);
  float mu = s1 * 0.015625f;
  float var = fmaf(-mu, mu, s2 * 0.015625f);
  return (t - mu) * rsqrtf(var + 1e-5f) * g + b;
}

// A&S 7.1.27: erf(x) ~= 1 - 1/poly^4, |err|<=5e-4; single v_rcp.
__device__ __forceinline__ float erf_fast(float x) {
  float ax = fabsf(x);
  float p = fmaf(fmaf(fmaf(fmaf(0.078108f, ax, 0.000972f), ax, 0.230389f),
                      ax, 0.278393f), ax, 1.0f);
  p = p * p;
  p = p * p;
  float r = __builtin_amdgcn_rcpf(p);
  return copysignf(1.0f - r, x);
}

__device__ __forceinline__ float gelu_exact(float v) {
  float half = 0.5f * v;
  return fmaf(half, erf_fast(v * 0.70710678118654752440f), half);
}

__device__ __forceinline__ float lane_bcast(float v, int k) {
  return __uint_as_float(__builtin_amdgcn_readlane(__float_as_uint(v), k));
}

// float -> bf16 (RNE)
__device__ __forceinline__ short f2bf(float f) {
  union { float f; unsigned u; } v; v.f = f;
  unsigned r = v.u + 0x7fffu + ((v.u >> 16) & 1u);
  return (short)(r >> 16);
}

// ---------------- init stage 1: prep_w | hist -------------------------------
__global__ __launch_bounds__(256) void k_init1(
    const float* __restrict__ conv_w, ushort* __restrict__ wt,
    const int* __restrict__ ei, int* __restrict__ csr,
    int ne, int oHist) {
  const int bid = blockIdx.x;
  const int tid = threadIdx.x;
  if (bid < oHist) {  // prep_w: 3*64*96 = 18432 elems, 72 blocks
    const int i = bid * 256 + tid;
    const int k = i % 96, f = (i / 96) % 64, l = i / (96 * 64);
    const float v = (k < 66) ? conv_w[(size_t)l * 66 * 64 + k * 64 + f] : 0.0f;
    wt[i] = (ushort)f2bf(v);
    return;
  }
  const int i = (bid - oHist) * 256 + tid;   // degree histogram
  if (i < ne) atomicAdd(&csr[__builtin_nontemporal_load(ei + ne + i)], 1);
}

// Single-block exclusive scan + wave partition emission.
// After: buf[i] = exclusive start of node i (scatter mutates into ends).
// wstart[w] = first node whose END exceeds T(w) = w*NE/NWV; wstart[NWV]=n.
__global__ __launch_bounds__(1024) void k_scan_fast(int* __restrict__ buf,
                                                    int* __restrict__ wstart,
                                                    int n, int nwv) {
  __shared__ int wsum[16];
  const int tid = threadIdx.x, lane = tid & 63, w = tid >> 6;
  const int chunk = (((n + 1023) / 1024) + 3) & ~3;   // multiple of 4
  const int a = min(tid * chunk, n), b = min(a + chunk, n);
  const bool full = (a + chunk <= n);
  int s = 0;
  if (full) {
    const int4* p4 = (const int4*)(buf + a);
#pragma unroll 4
    for (int i = 0; i < chunk / 4; i++) {
      int4 v = p4[i];
      s += v.x + v.y + v.z + v.w;
    }
  } else {
    for (int i = a; i < b; i++) s += buf[i];
  }
  int inc = s;
#pragma unroll
  for (int sh = 1; sh < 64; sh <<= 1) {
    int t = __shfl_up(inc, sh, 64);
    if (lane >= sh) inc += t;
  }
  if (lane == 63) wsum[w] = inc;
  __syncthreads();
  int wb = 0;
  for (int j = 0; j < w; j++) wb += wsum[j];
  int total = 0;
#pragma unroll
  for (int j = 0; j < 16; j++) total += wsum[j];
  int excl = wb + inc - s;

  // emit wstart[w] for all T(w) in [st, en) of each node
#define EMITW(idx, st, en)                                                    \
  {                                                                           \
    if ((en) > (st)) {                                                        \
      int wlo = (int)(((long long)(st) * nwv + total - 1) / total);           \
      int whi = (int)(((long long)(en) * nwv + total - 1) / total);           \
      for (int ww = wlo; ww < whi; ww++) wstart[ww] = (idx);                  \
    }                                                                         \
  }

  if (full) {
    int4* p4 = (int4*)(buf + a);
#pragma unroll 4
    for (int i = 0; i < chunk / 4; i++) {
      int4 v = p4[i];
      int4 o;
      o.x = excl; EMITW(a + i * 4 + 0, excl, excl + v.x); excl += v.x;
      o.y = excl; EMITW(a + i * 4 + 1, excl, excl + v.y); excl += v.y;
      o.z = excl; EMITW(a + i * 4 + 2, excl, excl + v.z); excl += v.z;
      o.w = excl; EMITW(a + i * 4 + 3, excl, excl + v.w); excl += v.w;
      p4[i] = o;
    }
  } else {
    for (int i = a; i < b; i++) {
      int v = buf[i];
      buf[i] = excl;
      EMITW(i, excl, excl + v);
      excl += v;
    }
  }
#undef EMITW
  if (tid == 0) wstart[nwv] = n;
}

// ---------------- init stage 2: XCD-partitioned scatter | embed -------------
// (R17 proven form: per-node cursors, role = bid&7, nt streams)
__global__ __launch_bounds__(256) void k_combo(
    const int* __restrict__ ei, const float* __restrict__ ea,
    int* __restrict__ cursor, int4* __restrict__ edata,
    const float* __restrict__ x,
    const float* __restrict__ w1, const float* __restrict__ b1,
    const float* __restrict__ g1, const float* __restrict__ be1,
    const float* __restrict__ w2, const float* __restrict__ b2,
    const float* __restrict__ g2, const float* __restrict__ be2,
    float* __restrict__ h, ushort* __restrict__ hb,
    int n_nodes, int ne, int nOrd, int embWaves, float roleScale) {
  const int bid = blockIdx.x;
  const int tid = threadIdx.x;
  const int sub = bid & 31;
  if (sub < 24) {  // ---- scatter (role-partitioned) ----
    const int role = bid & 7;
    const int ord = (bid >> 5) * 3 + (sub >> 3);     // ordinal within role
    const int lo = (int)((long long)ord * ne / nOrd);
    const int hi = (int)((long long)(ord + 1) * ne / nOrd);
    for (int i = lo + tid; i < hi; i += 256) {
      const int d = __builtin_nontemporal_load(ei + ne + i);   // nt: stream
      const int rd = min(7, (int)((float)d * roleScale));
      if (rd == role) {
        const int s = __builtin_nontemporal_load(ei + i);      // nt: stream
        const unsigned long long eau =
            __builtin_nontemporal_load((const unsigned long long*)ea + i);
        const float e0 = __uint_as_float((unsigned)eau);
        const float e1 = __uint_as_float((unsigned)(eau >> 32));
        const unsigned pk = (unsigned)(ushort)f2bf(e0) |
                            ((unsigned)(ushort)f2bf(e1) << 16);
        const int pos = atomicAdd(&cursor[d], 1);
        edata[pos] = make_int4(s, (int)pk, d, 0);   // cached: merges in L2
      }
    }
    return;
  }
  // ---- node embedding ----
  const int lane = tid & 63;
  const int eblk = (bid >> 5) * 8 + (sub - 24);
  const int wid = (eblk * 256 + tid) >> 6;
  const int nw = embWaves;
  float wc[64];
#pragma unroll
  for (int k = 0; k < 64; k++) wc[k] = w2[k * 64 + lane];
  const float w1a = w1[lane], w1b = w1[64 + lane];
  const float vb1 = b1[lane], vg1 = g1[lane], vbe1 = be1[lane];
  const float vb2 = b2[lane], vg2 = g2[lane], vbe2 = be2[lane];
  for (int n = wid; n < n_nodes; n += nw) {
    const float x0 = x[2 * n], x1 = x[2 * n + 1];
    float t = fmaf(x0, w1a, fmaf(x1, w1b, vb1));
    t = gelu_exact(ln_apply(t, vg1, vbe1));
    float a0 = vb2, a1 = 0.f, a2 = 0.f, a3 = 0.f;
#pragma unroll
    for (int k = 0; k < 64; k += 4) {
      a0 = fmaf(lane_bcast(t, k + 0), wc[k + 0], a0);
      a1 = fmaf(lane_bcast(t, k + 1), wc[k + 1], a1);
      a2 = fmaf(lane_bcast(t, k + 2), wc[k + 2], a2);
      a3 = fmaf(lane_bcast(t, k + 3), wc[k + 3], a3);
    }
    float acc = (a0 + a1) + (a2 + a3);
    acc = gelu_exact(ln_apply(acc, vg2, vbe2));
    __builtin_nontemporal_store(acc, h + (size_t)n * 64 + lane);   // nt
    __builtin_nontemporal_store((ushort)f2bf(acc),
                                hb + (size_t)n * 64 + lane);       // nt
  }
}

// per-node epilogue: a = tot/deg + h ; LN ; LN ; residual ; store h (+hb)
__device__ __forceinline__ void node_finish(
    float tot, float dgf, float hv, int d, int lane,
    float ngv, float nbv, float ogv, float obv,
    float* __restrict__ h, ushort* __restrict__ hb_out, int writeHb) {
  const float a = tot / dgf + hv;
  const float c = ln_apply(a, ngv, nbv);
  const float o = ln_apply(c, ogv, obv);
  const float outv = hv + o;
  __builtin_nontemporal_store(outv, h + (size_t)d * 64 + lane);
  if (writeHb)
    __builtin_nontemporal_store((ushort)f2bf(outv),
                                hb_out + (size_t)d * 64 + lane);
}

// ---------------- fused layer kernel: one wave owns a node range ------------
// Contiguous edge range (csr post-scatter = ends); 16-edge MFMA tiles exactly
// as R17; register carry per open node; inline finish at node completion.
__global__ __launch_bounds__(256, 3) void k_layer(
    const ushort* __restrict__ hb_in, ushort* __restrict__ hb_out,
    float* __restrict__ h,
    const int4* __restrict__ edata, const int* __restrict__ csr,
    const int* __restrict__ wstart, const ushort* __restrict__ wt,
    const float* __restrict__ bias, const float* __restrict__ mg,
    const float* __restrict__ mb,
    const float* __restrict__ ng, const float* __restrict__ nb,
    const float* __restrict__ og, const float* __restrict__ ob,
    int writeHb) {
  __shared__ __align__(16) ushort lwt[64 * 96];   // 12 KB: B^T tiles
  {
    const uint4* s = (const uint4*)wt;
    uint4* d = (uint4*)lwt;
    for (int i = threadIdx.x; i < 768; i += 256) d[i] = s[i];
  }
  __syncthreads();

  const int lane = threadIdx.x & 63;
  const int wgl = (int)((blockIdx.x * blockDim.x + threadIdx.x) >> 6);
  const int n0 = wstart[wgl], n1 = wstart[wgl + 1];
  if (n0 >= n1) return;
  const int e_lo = (n0 > 0) ? csr[n0 - 1] : 0;   // csr = ends post-scatter
  const int e_hi = csr[n1 - 1];

  const int grp = lane >> 4, col = lane & 15;
  const float ngv = ng[lane], nbv = nb[lane];
  const float ogv = og[lane], obv = ob[lane];

  float vb[4], vg[4], vbb[4];
#pragma unroll
  for (int t = 0; t < 4; t++) {
    const int f = t * 16 + col;
    vb[t] = bias[f]; vg[t] = mg[f]; vbb[t] = mb[f];
  }

  int nextn = n0;        // next node to account for (deg0 sweep)
  int nstart = e_lo;     // edge index where current open node began
  float car[4] = {0.f, 0.f, 0.f, 0.f};

  const int nch = (e_hi - e_lo + 15) >> 4;
  if (nch > 0) {
    int slot = min(e_lo + col, e_hi - 1);
    int4 e = edata[slot];
    const ushort* hp0 = hb_in + (size_t)e.x * 64 + grp * 8;
    bfrag A0 = *(const bfrag*)(hp0);
    bfrag A1 = *(const bfrag*)(hp0 + 32);

    for (int c = 0;;) {
      const int rem = min(16, e_hi - e_lo - 16 * c);
      const bool more = (c + 1) < nch;
      const int nslot = more ? min(e_lo + 16 * (c + 1) + col, e_hi - 1) : slot;
      const int4 en = edata[nslot];   // prefetch next tile payload

      // prefetch h row of the node open at tile start (likely completer)
      const int d0t = __builtin_amdgcn_readlane(e.z, 0);
      const float hpre = h[(size_t)d0t * 64 + lane];

      bfrag A2 = {0, 0, 0, 0, 0, 0, 0, 0};
      if (grp == 0) {
        A2[0] = (short)(e.y & 0xffff);
        A2[1] = (short)((unsigned)e.y >> 16);
      }

      ffrag acc[4];
#pragma unroll
      for (int t = 0; t < 4; t++) { ffrag cc = {vb[t], vb[t], vb[t], vb[t]}; acc[t] = cc; }
#pragma unroll
      for (int t = 0; t < 4; t++) {
        const bfrag B = *(const bfrag*)(lwt + (t * 16 + col) * 96 + grp * 8);
        acc[t] = __builtin_amdgcn_mfma_f32_16x16x32_bf16(A0, B, acc[t], 0, 0, 0);
      }
#pragma unroll
      for (int t = 0; t < 4; t++) {
        const bfrag B = *(const bfrag*)(lwt + (t * 16 + col) * 96 + 32 + grp * 8);
        acc[t] = __builtin_amdgcn_mfma_f32_16x16x32_bf16(A1, B, acc[t], 0, 0, 0);
      }
#pragma unroll
      for (int t = 0; t < 4; t++) {
        const bfrag B = *(const bfrag*)(lwt + (t * 16 + col) * 96 + 64 + grp * 8);
        acc[t] = __builtin_amdgcn_mfma_f32_16x16x32_bf16(A2, B, acc[t], 0, 0, 0);
      }

      // prefetch next tile's gather
      const ushort* hq = hb_in + (size_t)en.x * 64 + grp * 8;
      const bfrag N0 = *(const bfrag*)(hq);
      const bfrag N1 = *(const bfrag*)(hq + 32);

      // ---- per-edge LN stats (rows m = grp*4+r) ----
      float sx[4], sq[4];
#pragma unroll
      for (int r = 0; r < 4; r++) {
        float s = (acc[0][r] + acc[1][r]) + (acc[2][r] + acc[3][r]);
        float q = fmaf(acc[0][r], acc[0][r], fmaf(acc[1][r], acc[1][r],
                  fmaf(acc[2][r], acc[2][r], acc[3][r] * acc[3][r])));
        sx[r] = s; sq[r] = q;
      }
#pragma unroll
      for (int r = 0; r < 4; r++) sx[r] = rsum16(sx[r]);
#pragma unroll
      for (int r = 0; r < 4; r++) sq[r] = rsum16(sq[r]);
      float iv[4], mi[4];
#pragma unroll
      for (int r = 0; r < 4; r++) {
        const float mu = sx[r] * 0.015625f;
        const float var = fmaf(-mu, mu, sq[r] * 0.015625f);
        iv[r] = rsqrtf(var + 1e-5f);
        mi[r] = -mu * iv[r];
      }

      // ---- LN-apply + GELU, in place ----
#pragma unroll
      for (int t = 0; t < 4; t++) {
#pragma unroll
        for (int r = 0; r < 4; r++) {
          const float z = fmaf(acc[t][r], iv[r], mi[r]);
          acc[t][r] = gelu_exact(fmaf(z, vg[t], vbb[t]));
        }
      }

      // ---- segment walk (dst non-decreasing; segments end at node bounds) --
      const int prev = __shfl_up(e.z, 1, 64);
      const unsigned long long bal = __ballot((col > 0) && (e.z != prev));
      const unsigned bm = (unsigned)bal & 0xFFFEu;
      const int peek = more ? __builtin_amdgcn_readlane(en.z, 0) : -1;

      int s0 = 0;
      while (s0 < rem) {
        const unsigned rest = bm >> (s0 + 1);
        int s1 = rest ? (s0 + 1 + __builtin_ctz(rest)) : 16;
        if (s1 > rem) s1 = rem;
        const int dseg = __builtin_amdgcn_readlane(e.z, s0);

        float rs[4];
#pragma unroll
        for (int t = 0; t < 4; t++) {
          float r_ = 0.f;
#pragma unroll
          for (int r = 0; r < 4; r++) {
            const int row = grp * 4 + r;
            const float w = (row >= s0 && row < s1) ? 1.0f : 0.0f;
            r_ = fmaf(acc[t][r], w, r_);
          }
          r_ += __shfl_xor(r_, 16, 64);
          r_ += __shfl_xor(r_, 32, 64);
          rs[t] = r_;
        }

        const bool comp = (s1 < rem) || (!more) || (peek != dseg);
        if (comp) {
          for (int n = nextn; n < dseg; n++) {   // deg-0 sweep (rare)
            const float hv0 = h[(size_t)n * 64 + lane];
            node_finish(0.f, 1.f, hv0, n, lane, ngv, nbv, ogv, obv,
                        h, hb_out, writeHb);
          }
          const float t0 = __shfl(car[0] + rs[0], lane & 15, 64);
          const float t1 = __shfl(car[1] + rs[1], lane & 15, 64);
          const float t2 = __shfl(car[2] + rs[2], lane & 15, 64);
          const float t3 = __shfl(car[3] + rs[3], lane & 15, 64);
          const float tot = (lane < 16) ? t0 : (lane < 32) ? t1
                              : (lane < 48) ? t2 : t3;
          const int glob = e_lo + 16 * c + s1;
          const float dgf = (float)(glob - nstart);
          const float hv = (dseg == d0t) ? hpre : h[(size_t)dseg * 64 + lane];
          node_finish(tot, dgf, hv, dseg, lane, ngv, nbv, ogv, obv,
                      h, hb_out, writeHb);
          car[0] = car[1] = car[2] = car[3] = 0.f;
          nstart = glob;
          nextn = dseg + 1;
        } else {
#pragma unroll
          for (int t = 0; t < 4; t++) car[t] += rs[t];
        }
        s0 = s1;
      }

      if (!more) break;
      c++; slot = nslot; e = en; A0 = N0; A1 = N1;
    }
  }
  // trailing deg-0 nodes
  for (int n = nextn; n < n1; n++) {
    const float hv0 = h[(size_t)n * 64 + lane];
    node_finish(0.f, 1.f, hv0, n, lane, ngv, nbv, ogv, obv,
                h, hb_out, writeHb);
  }
}

// ------------------------------ pooling (segmented) -------------------------
__global__ void k_pool_seg(const float* __restrict__ h, const int* __restrict__ batch,
                           float* __restrict__ g, float* __restrict__ cnt,
                           int n_nodes, int chunk) {
  const int lane = threadIdx.x & 63;
  const int wid = (blockIdx.x * blockDim.x + threadIdx.x) >> 6;
  const int n0 = wid * chunk;
  if (n0 >= n_nodes) return;
  const int n1 = min(n0 + chunk, n_nodes);
  int cur = batch[n0], c = 0;
  float acc = 0.f;
  for (int n = n0; n < n1; n++) {
    const int b = batch[n];
    if (b != cur) {
      atomicAdd(&g[(size_t)cur * 64 + lane], acc);
      if (lane == 0) atomicAdd(&cnt[cur], (float)c);
      acc = 0.f; c = 0; cur = b;
    }
    acc += h[(size_t)n * 64 + lane];
    c++;
  }
  atomicAdd(&g[(size_t)cur * 64 + lane], acc);
  if (lane == 0) atomicAdd(&cnt[cur], (float)c);
}

// ------------------------------- head --------------------------------------
__global__ void k_head(const float* __restrict__ g, const float* __restrict__ cnt,
                       const float* __restrict__ w1, const float* __restrict__ b1,
                       const float* __restrict__ g1, const float* __restrict__ be1,
                       const float* __restrict__ w2, const float* __restrict__ b2,
                       const float* __restrict__ g2, const float* __restrict__ be2,
                       const float* __restrict__ w3, const float* __restrict__ b3,
                       float* __restrict__ out, int nb_) {
  const int lane = threadIdx.x & 63;
  const int row = (blockIdx.x * blockDim.x + threadIdx.x) >> 6;
  if (row >= nb_) return;
  const float c = fmaxf(cnt[row], 1.0f);
  const float gv = g[row * 64 + lane] / c;
  float a0 = b1[lane], a1 = 0.f, a2 = 0.f, a3 = 0.f;
#pragma unroll
  for (int k = 0; k < 64; k += 4) {
    a0 = fmaf(lane_bcast(gv, k + 0), w1[(k + 0) * 64 + lane], a0);
    a1 = fmaf(lane_bcast(gv, k + 1), w1[(k + 1) * 64 + lane], a1);
    a2 = fmaf(lane_bcast(gv, k + 2), w1[(k + 2) * 64 + lane], a2);
    a3 = fmaf(lane_bcast(gv, k + 3), w1[(k + 3) * 64 + lane], a3);
  }
  float t = (a0 + a1) + (a2 + a3);
  t = fmaxf(ln_apply(t, g1[lane], be1[lane]), 0.0f);

  const int j = lane & 31;
  float c0 = b2[j], c1 = 0.f, c2 = 0.f, c3 = 0.f;
#pragma unroll
  for (int k = 0; k < 64; k += 4) {
    c0 = fmaf(lane_bcast(t, k + 0), w2[(k + 0) * 32 + j], c0);
    c1 = fmaf(lane_bcast(t, k + 1), w2[(k + 1) * 32 + j], c1);
    c2 = fmaf(lane_bcast(t, k + 2), w2[(k + 2) * 32 + j], c2);
    c3 = fmaf(lane_bcast(t, k + 3), w2[(k + 3) * 32 + j], c3);
  }
  float t2 = (c0 + c1) + (c2 + c3);
  t2 = fmaxf(ln_apply(t2, g2[j], be2[j]), 0.0f);
  const float p = t2 * w3[j];
  const float s = wave_sum64(p) * 0.5f;
  if (lane == 0) out[row] = s + b3[0];
}

// ---------------------------------------------------------------------------
extern "C" void kernel_launch(void* const* d_in, const int* in_sizes, int n_in,
                              void* d_out, int out_size, void* d_ws, size_t ws_size,
                              hipStream_t stream) {
  const float* x      = (const float*)d_in[0];
  const float* ea     = (const float*)d_in[1];
  const float* ne_w1  = (const float*)d_in[2];
  const float* ne_b1  = (const float*)d_in[3];
  const float* ne_g1  = (const float*)d_in[4];
  const float* ne_be1 = (const float*)d_in[5];
  const float* ne_w2  = (const float*)d_in[6];
  const float* ne_b2  = (const float*)d_in[7];
  const float* ne_g2  = (const float*)d_in[8];
  const float* ne_be2 = (const float*)d_in[9];
  const float* conv_w = (const float*)d_in[10];
  const float* conv_b = (const float*)d_in[11];
  const float* conv_mg= (const float*)d_in[12];
  const float* conv_mb= (const float*)d_in[13];
  const float* conv_ng= (const float*)d_in[14];
  const float* conv_nb= (const float*)d_in[15];
  const float* out_ng = (const float*)d_in[16];
  const float* out_nb = (const float*)d_in[17];
  const float* m_w1   = (const float*)d_in[18];
  const float* m_b1   = (const float*)d_in[19];
  const float* m_g1   = (const float*)d_in[20];
  const float* m_be1  = (const float*)d_in[21];
  const float* m_w2   = (const float*)d_in[22];
  const float* m_b2   = (const float*)d_in[23];
  const float* m_g2   = (const float*)d_in[24];
  const float* m_be2  = (const float*)d_in[25];
  const float* m_w3   = (const float*)d_in[26];
  const float* m_b3   = (const float*)d_in[27];
  const int*   eidx   = (const int*)d_in[28];
  const int*   batch  = (const int*)d_in[29];
  float* outp = (float*)d_out;

  const int NN = in_sizes[29];
  const int NE = in_sizes[1] / 2;
  const int NB = out_size;

  // workspace
  char* wsb = (char*)d_ws;
  float*  h     = (float*)wsb;                            // NN*64 f32
  ushort* hbA   = (ushort*)(h + (size_t)NN * 64);         // NN*64 bf16
  ushort* hbB   = hbA + (size_t)NN * 64;                  // NN*64 bf16
  int4*   edata = (int4*)(hbB + (size_t)NN * 64);         // NE int4
  ushort* wt    = (ushort*)(edata + NE);                  // 3*64*96 bf16
  int*    wstart= (int*)(wt + 3 * 64 * 96);               // NWV+1 int
  float*  gbuf  = (float*)(wstart + (NWV + 1));           // NB*64 f32  --+
  float*  cnt   = gbuf + (size_t)NB * 64;                 // NB f32       | zero
  int*    csr   = (int*)(cnt + NB);                       // NN int     --+

  const dim3 blk(256);

  // zero gbuf + cnt + csr in one contiguous memset (agg is gone)
  const size_t zbytes = (char*)(csr + NN) - (char*)gbuf;
  hipMemsetAsync(gbuf, 0, zbytes, stream);

  // stage 1: prep(72) | hist
  const int nPrep = (3 * 64 * 96) / 256;              // 72
  const int nHist = (NE + 255) / 256;
  k_init1<<<nPrep + nHist, blk, 0, stream>>>(conv_w, wt, eidx, csr, NE, nPrep);

  k_scan_fast<<<1, 1024, 0, stream>>>(csr, wstart, NN, NWV);

  // stage 2: XCD-partitioned scatter | embed (R17 proven)
  const int ngroups = 261;                            // 24 scat + 8 emb per group
  const int nOrd = ngroups * 3;
  const int nEmb = ngroups * 8;
  k_combo<<<ngroups * 32, blk, 0, stream>>>(
      eidx, ea, csr, edata, x,
      ne_w1, ne_b1, ne_g1, ne_be1, ne_w2, ne_b2, ne_g2, ne_be2,
      h, hbA, NN, NE, nOrd, nEmb * 4, 8.0f / (float)NN);

  // 3 fused layers (hb ping-pong; h in place, owner-exclusive)
  for (int l = 0; l < 3; l++) {
    const ushort* hin = (l == 1) ? hbB : hbA;
    ushort* hout = (l == 0) ? hbB : hbA;
    k_layer<<<NWV / 4, blk, 0, stream>>>(
        hin, hout, h, edata, csr, wstart, wt + (size_t)l * 64 * 96,
        conv_b + l * 64, conv_mg + l * 64, conv_mb + l * 64,
        conv_ng + l * 64, conv_nb + l * 64,
        out_ng + l * 64, out_nb + l * 64, (l < 2) ? 1 : 0);
  }

  {
    const int chunk = 32;
    const int nwaves = (NN + chunk - 1) / chunk;
    const int nblocks = (nwaves * 64 + 255) / 256;
    k_pool_seg<<<nblocks, blk, 0, stream>>>(h, batch, gbuf, cnt, NN, chunk);
  }
  k_head<<<(NB + 3) / 4, blk, 0, stream>>>(gbuf, cnt, m_w1, m_b1, m_g1, m_be1,
                                           m_w2, m_b2, m_g2, m_be2, m_w3, m_b3,
                                           outp, NB);
}

// Round 6
// 813.385 us; speedup vs baseline: 3.1105x; 1.0609x over previous
//
#include <hip/hip_runtime.h>
#include <math.h>

// ---------------------------------------------------------------------------
// VertexGNN on MI355X — round 21 = R20 resubmit (infra flake: container
// failed twice, no counters). R20 = R19 minus the scan-side partition:
// k_layer waves self-partition with two binary searches over csr
// (post-scatter csr[i] = end_i; wstart[w] = first i with end_i > T(w));
// scan is the pristine R17 form. Partition provably identical to R19's
// EMITW. Everything else = R19 (fused layer kernel, hb ping-pong, no agg
// array/atomics/memset).
// ---------------------------------------------------------------------------

typedef __attribute__((ext_vector_type(8))) short bfrag;   // 8 x bf16
typedef __attribute__((ext_vector_type(4))) float ffrag;   // 4 x f32

#define NWV 16384   // waves in k_layer (4096 blocks x 4 waves)

template <int CTRL>
__device__ __forceinline__ float dpp_mov(float v) {
  return __int_as_float(
      __builtin_amdgcn_update_dpp(0, __float_as_int(v), CTRL, 0xF, 0xF, true));
}

__device__ __forceinline__ float rsum16(float v) {
  v += dpp_mov<0x128>(v);   // row_ror:8
  v += dpp_mov<0x124>(v);   // row_ror:4
  v += dpp_mov<0x122>(v);   // row_ror:2
  v += dpp_mov<0x121>(v);   // row_ror:1
  return v;
}

__device__ __forceinline__ float wave_sum64(float v) {
  v = rsum16(v);
  v += __shfl_xor(v, 16, 64);
  v += __shfl_xor(v, 32, 64);
  return v;
}

// LN with independent E[x], E[x^2] reductions (chains overlap)
__device__ __forceinline__ float ln_apply(float t, float g, float b) {
  float s1 = wave_sum64(t);
  float s2 = wave_sum64(t * t);
  float mu = s1 * 0.015625f;
  float var = fmaf(-mu, mu, s2 * 0.015625f);
  return (t - mu) * rsqrtf(var + 1e-5f) * g + b;
}

// A&S 7.1.27: erf(x) ~= 1 - 1/poly^4, |err|<=5e-4; single v_rcp.
__device__ __forceinline__ float erf_fast(float x) {
  float ax = fabsf(x);
  float p = fmaf(fmaf(fmaf(fmaf(0.078108f, ax, 0.000972f), ax, 0.230389f),
                      ax, 0.278393f), ax, 1.0f);
  p = p * p;
  p = p * p;
  float r = __builtin_amdgcn_rcpf(p);
  return copysignf(1.0f - r, x);
}

__device__ __forceinline__ float gelu_exact(float v) {
  float half = 0.5f * v;
  return fmaf(half, erf_fast(v * 0.70710678118654752440f), half);
}

__device__ __forceinline__ float lane_bcast(float v, int k) {
  return __uint_as_float(__builtin_amdgcn_readlane(__float_as_uint(v), k));
}

// float -> bf16 (RNE)
__device__ __forceinline__ short f2bf(float f) {
  union { float f; unsigned u; } v; v.f = f;
  unsigned r = v.u + 0x7fffu + ((v.u >> 16) & 1u);
  return (short)(r >> 16);
}

// first index i in [0,n) with a[i] > T; returns n if none (wave-uniform)
__device__ __forceinline__ int ub_search(const int* __restrict__ a, int n,
                                         long long T) {
  int lo = 0, hi = n;
  while (lo < hi) {
    const int mid = (lo + hi) >> 1;
    if ((long long)a[mid] > T) hi = mid; else lo = mid + 1;
  }
  return lo;
}

// ---------------- init stage 1: prep_w | hist -------------------------------
__global__ __launch_bounds__(256) void k_init1(
    const float* __restrict__ conv_w, ushort* __restrict__ wt,
    const int* __restrict__ ei, int* __restrict__ csr,
    int ne, int oHist) {
  const int bid = blockIdx.x;
  const int tid = threadIdx.x;
  if (bid < oHist) {  // prep_w: 3*64*96 = 18432 elems, 72 blocks
    const int i = bid * 256 + tid;
    const int k = i % 96, f = (i / 96) % 64, l = i / (96 * 64);
    const float v = (k < 66) ? conv_w[(size_t)l * 66 * 64 + k * 64 + f] : 0.0f;
    wt[i] = (ushort)f2bf(v);
    return;
  }
  const int i = (bid - oHist) * 256 + tid;   // degree histogram
  if (i < ne) atomicAdd(&csr[__builtin_nontemporal_load(ei + ne + i)], 1);
}

// Single-block exclusive scan, int4-vectorized chunks (R17 pristine form).
__global__ __launch_bounds__(1024) void k_scan_fast(int* __restrict__ buf, int n) {
  __shared__ int wsum[16];
  const int tid = threadIdx.x, lane = tid & 63, w = tid >> 6;
  const int chunk = (((n + 1023) / 1024) + 3) & ~3;   // multiple of 4
  const int a = min(tid * chunk, n), b = min(a + chunk, n);
  const bool full = (a + chunk <= n);
  int s = 0;
  if (full) {
    const int4* p4 = (const int4*)(buf + a);
#pragma unroll 4
    for (int i = 0; i < chunk / 4; i++) {
      int4 v = p4[i];
      s += v.x + v.y + v.z + v.w;
    }
  } else {
    for (int i = a; i < b; i++) s += buf[i];
  }
  int inc = s;
#pragma unroll
  for (int sh = 1; sh < 64; sh <<= 1) {
    int t = __shfl_up(inc, sh, 64);
    if (lane >= sh) inc += t;
  }
  if (lane == 63) wsum[w] = inc;
  __syncthreads();
  int wb = 0;
  for (int j = 0; j < w; j++) wb += wsum[j];
  int excl = wb + inc - s;
  if (full) {
    int4* p4 = (int4*)(buf + a);
#pragma unroll 4
    for (int i = 0; i < chunk / 4; i++) {
      int4 v = p4[i];
      int4 o;
      o.x = excl; excl += v.x;
      o.y = excl; excl += v.y;
      o.z = excl; excl += v.z;
      o.w = excl; excl += v.w;
      p4[i] = o;
    }
  } else {
    for (int i = a; i < b; i++) { int v = buf[i]; buf[i] = excl; excl += v; }
  }
}

// ---------------- init stage 2: XCD-partitioned scatter | embed -------------
// (R17 proven form: per-node cursors, role = bid&7, nt streams)
__global__ __launch_bounds__(256) void k_combo(
    const int* __restrict__ ei, const float* __restrict__ ea,
    int* __restrict__ cursor, int4* __restrict__ edata,
    const float* __restrict__ x,
    const float* __restrict__ w1, const float* __restrict__ b1,
    const float* __restrict__ g1, const float* __restrict__ be1,
    const float* __restrict__ w2, const float* __restrict__ b2,
    const float* __restrict__ g2, const float* __restrict__ be2,
    float* __restrict__ h, ushort* __restrict__ hb,
    int n_nodes, int ne, int nOrd, int embWaves, float roleScale) {
  const int bid = blockIdx.x;
  const int tid = threadIdx.x;
  const int sub = bid & 31;
  if (sub < 24) {  // ---- scatter (role-partitioned) ----
    const int role = bid & 7;
    const int ord = (bid >> 5) * 3 + (sub >> 3);     // ordinal within role
    const int lo = (int)((long long)ord * ne / nOrd);
    const int hi = (int)((long long)(ord + 1) * ne / nOrd);
    for (int i = lo + tid; i < hi; i += 256) {
      const int d = __builtin_nontemporal_load(ei + ne + i);   // nt: stream
      const int rd = min(7, (int)((float)d * roleScale));
      if (rd == role) {
        const int s = __builtin_nontemporal_load(ei + i);      // nt: stream
        const unsigned long long eau =
            __builtin_nontemporal_load((const unsigned long long*)ea + i);
        const float e0 = __uint_as_float((unsigned)eau);
        const float e1 = __uint_as_float((unsigned)(eau >> 32));
        const unsigned pk = (unsigned)(ushort)f2bf(e0) |
                            ((unsigned)(ushort)f2bf(e1) << 16);
        const int pos = atomicAdd(&cursor[d], 1);
        edata[pos] = make_int4(s, (int)pk, d, 0);   // cached: merges in L2
      }
    }
    return;
  }
  // ---- node embedding ----
  const int lane = tid & 63;
  const int eblk = (bid >> 5) * 8 + (sub - 24);
  const int wid = (eblk * 256 + tid) >> 6;
  const int nw = embWaves;
  float wc[64];
#pragma unroll
  for (int k = 0; k < 64; k++) wc[k] = w2[k * 64 + lane];
  const float w1a = w1[lane], w1b = w1[64 + lane];
  const float vb1 = b1[lane], vg1 = g1[lane], vbe1 = be1[lane];
  const float vb2 = b2[lane], vg2 = g2[lane], vbe2 = be2[lane];
  for (int n = wid; n < n_nodes; n += nw) {
    const float x0 = x[2 * n], x1 = x[2 * n + 1];
    float t = fmaf(x0, w1a, fmaf(x1, w1b, vb1));
    t = gelu_exact(ln_apply(t, vg1, vbe1));
    float a0 = vb2, a1 = 0.f, a2 = 0.f, a3 = 0.f;
#pragma unroll
    for (int k = 0; k < 64; k += 4) {
      a0 = fmaf(lane_bcast(t, k + 0), wc[k + 0], a0);
      a1 = fmaf(lane_bcast(t, k + 1), wc[k + 1], a1);
      a2 = fmaf(lane_bcast(t, k + 2), wc[k + 2], a2);
      a3 = fmaf(lane_bcast(t, k + 3), wc[k + 3], a3);
    }
    float acc = (a0 + a1) + (a2 + a3);
    acc = gelu_exact(ln_apply(acc, vg2, vbe2));
    __builtin_nontemporal_store(acc, h + (size_t)n * 64 + lane);   // nt
    __builtin_nontemporal_store((ushort)f2bf(acc),
                                hb + (size_t)n * 64 + lane);       // nt
  }
}

// per-node epilogue: a = tot/deg + h ; LN ; LN ; residual ; store h (+hb)
__device__ __forceinline__ void node_finish(
    float tot, float dgf, float hv, int d, int lane,
    float ngv, float nbv, float ogv, float obv,
    float* __restrict__ h, ushort* __restrict__ hb_out, int writeHb) {
  const float a = tot / dgf + hv;
  const float c = ln_apply(a, ngv, nbv);
  const float o = ln_apply(c, ogv, obv);
  const float outv = hv + o;
  __builtin_nontemporal_store(outv, h + (size_t)d * 64 + lane);
  if (writeHb)
    __builtin_nontemporal_store((ushort)f2bf(outv),
                                hb_out + (size_t)d * 64 + lane);
}

// ---------------- fused layer kernel: one wave owns a node range ------------
// Self-partition: csr post-scatter holds end_i; wave w owns nodes
// [ub(csr,T(w)), ub(csr,T(w+1))) — provably identical to R19's EMITW.
__global__ __launch_bounds__(256, 3) void k_layer(
    const ushort* __restrict__ hb_in, ushort* __restrict__ hb_out,
    float* __restrict__ h,
    const int4* __restrict__ edata, const int* __restrict__ csr,
    const ushort* __restrict__ wt,
    const float* __restrict__ bias, const float* __restrict__ mg,
    const float* __restrict__ mb,
    const float* __restrict__ ng, const float* __restrict__ nb,
    const float* __restrict__ og, const float* __restrict__ ob,
    int nn, int ne, int writeHb) {
  __shared__ __align__(16) ushort lwt[64 * 96];   // 12 KB: B^T tiles
  {
    const uint4* s = (const uint4*)wt;
    uint4* d = (uint4*)lwt;
    for (int i = threadIdx.x; i < 768; i += 256) d[i] = s[i];
  }
  __syncthreads();

  const int lane = threadIdx.x & 63;
  const int wgl = (int)((blockIdx.x * blockDim.x + threadIdx.x) >> 6);
  // ---- self-partition via binary search over ends (wave-uniform) ----
  const long long Ta = (long long)wgl * ne / NWV;
  const long long Tb = (long long)(wgl + 1) * ne / NWV;
  const int n0 = ub_search(csr, nn, Ta);
  const int n1 = (wgl + 1 == NWV) ? nn : ub_search(csr, nn, Tb);
  if (n0 >= n1) return;
  const int e_lo = (n0 > 0) ? csr[n0 - 1] : 0;   // end_{n0-1} = start_{n0}
  const int e_hi = csr[n1 - 1];

  const int grp = lane >> 4, col = lane & 15;
  const float ngv = ng[lane], nbv = nb[lane];
  const float ogv = og[lane], obv = ob[lane];

  float vb[4], vg[4], vbb[4];
#pragma unroll
  for (int t = 0; t < 4; t++) {
    const int f = t * 16 + col;
    vb[t] = bias[f]; vg[t] = mg[f]; vbb[t] = mb[f];
  }

  int nextn = n0;        // next node to account for (deg0 sweep)
  int nstart = e_lo;     // edge index where current open node began
  float car[4] = {0.f, 0.f, 0.f, 0.f};

  const int nch = (e_hi - e_lo + 15) >> 4;
  if (nch > 0) {
    int slot = min(e_lo + col, e_hi - 1);
    int4 e = edata[slot];
    const ushort* hp0 = hb_in + (size_t)e.x * 64 + grp * 8;
    bfrag A0 = *(const bfrag*)(hp0);
    bfrag A1 = *(const bfrag*)(hp0 + 32);

    for (int c = 0;;) {
      const int rem = min(16, e_hi - e_lo - 16 * c);
      const bool more = (c + 1) < nch;
      const int nslot = more ? min(e_lo + 16 * (c + 1) + col, e_hi - 1) : slot;
      const int4 en = edata[nslot];   // prefetch next tile payload

      // prefetch h row of the node open at tile start (likely completer)
      const int d0t = __builtin_amdgcn_readlane(e.z, 0);
      const float hpre = h[(size_t)d0t * 64 + lane];

      bfrag A2 = {0, 0, 0, 0, 0, 0, 0, 0};
      if (grp == 0) {
        A2[0] = (short)(e.y & 0xffff);
        A2[1] = (short)((unsigned)e.y >> 16);
      }

      ffrag acc[4];
#pragma unroll
      for (int t = 0; t < 4; t++) { ffrag cc = {vb[t], vb[t], vb[t], vb[t]}; acc[t] = cc; }
#pragma unroll
      for (int t = 0; t < 4; t++) {
        const bfrag B = *(const bfrag*)(lwt + (t * 16 + col) * 96 + grp * 8);
        acc[t] = __builtin_amdgcn_mfma_f32_16x16x32_bf16(A0, B, acc[t], 0, 0, 0);
      }
#pragma unroll
      for (int t = 0; t < 4; t++) {
        const bfrag B = *(const bfrag*)(lwt + (t * 16 + col) * 96 + 32 + grp * 8);
        acc[t] = __builtin_amdgcn_mfma_f32_16x16x32_bf16(A1, B, acc[t], 0, 0, 0);
      }
#pragma unroll
      for (int t = 0; t < 4; t++) {
        const bfrag B = *(const bfrag*)(lwt + (t * 16 + col) * 96 + 64 + grp * 8);
        acc[t] = __builtin_amdgcn_mfma_f32_16x16x32_bf16(A2, B, acc[t], 0, 0, 0);
      }

      // prefetch next tile's gather
      const ushort* hq = hb_in + (size_t)en.x * 64 + grp * 8;
      const bfrag N0 = *(const bfrag*)(hq);
      const bfrag N1 = *(const bfrag*)(hq + 32);

      // ---- per-edge LN stats (rows m = grp*4+r) ----
      float sx[4], sq[4];
#pragma unroll
      for (int r = 0; r < 4; r++) {
        float s = (acc[0][r] + acc[1][r]) + (acc[2][r] + acc[3][r]);
        float q = fmaf(acc[0][r], acc[0][r], fmaf(acc[1][r], acc[1][r],
                  fmaf(acc[2][r], acc[2][r], acc[3][r] * acc[3][r])));
        sx[r] = s; sq[r] = q;
      }
#pragma unroll
      for (int r = 0; r < 4; r++) sx[r] = rsum16(sx[r]);
#pragma unroll
      for (int r = 0; r < 4; r++) sq[r] = rsum16(sq[r]);
      float iv[4], mi[4];
#pragma unroll
      for (int r = 0; r < 4; r++) {
        const float mu = sx[r] * 0.015625f;
        const float var = fmaf(-mu, mu, sq[r] * 0.015625f);
        iv[r] = rsqrtf(var + 1e-5f);
        mi[r] = -mu * iv[r];
      }

      // ---- LN-apply + GELU, in place ----
#pragma unroll
      for (int t = 0; t < 4; t++) {
#pragma unroll
        for (int r = 0; r < 4; r++) {
          const float z = fmaf(acc[t][r], iv[r], mi[r]);
          acc[t][r] = gelu_exact(fmaf(z, vg[t], vbb[t]));
        }
      }

      // ---- segment walk (dst non-decreasing; segments end at node bounds) --
      const int prev = __shfl_up(e.z, 1, 64);
      const unsigned long long bal = __ballot((col > 0) && (e.z != prev));
      const unsigned bm = (unsigned)bal & 0xFFFEu;
      const int peek = more ? __builtin_amdgcn_readlane(en.z, 0) : -1;

      int s0 = 0;
      while (s0 < rem) {
        const unsigned rest = bm >> (s0 + 1);
        int s1 = rest ? (s0 + 1 + __builtin_ctz(rest)) : 16;
        if (s1 > rem) s1 = rem;
        const int dseg = __builtin_amdgcn_readlane(e.z, s0);

        float rs[4];
#pragma unroll
        for (int t = 0; t < 4; t++) {
          float r_ = 0.f;
#pragma unroll
          for (int r = 0; r < 4; r++) {
            const int row = grp * 4 + r;
            const float w = (row >= s0 && row < s1) ? 1.0f : 0.0f;
            r_ = fmaf(acc[t][r], w, r_);
          }
          r_ += __shfl_xor(r_, 16, 64);
          r_ += __shfl_xor(r_, 32, 64);
          rs[t] = r_;
        }

        const bool comp = (s1 < rem) || (!more) || (peek != dseg);
        if (comp) {
          for (int n = nextn; n < dseg; n++) {   // deg-0 sweep (rare)
            const float hv0 = h[(size_t)n * 64 + lane];
            node_finish(0.f, 1.f, hv0, n, lane, ngv, nbv, ogv, obv,
                        h, hb_out, writeHb);
          }
          const float t0 = __shfl(car[0] + rs[0], lane & 15, 64);
          const float t1 = __shfl(car[1] + rs[1], lane & 15, 64);
          const float t2 = __shfl(car[2] + rs[2], lane & 15, 64);
          const float t3 = __shfl(car[3] + rs[3], lane & 15, 64);
          const float tot = (lane < 16) ? t0 : (lane < 32) ? t1
                              : (lane < 48) ? t2 : t3;
          const int glob = e_lo + 16 * c + s1;
          const float dgf = (float)(glob - nstart);
          const float hv = (dseg == d0t) ? hpre : h[(size_t)dseg * 64 + lane];
          node_finish(tot, dgf, hv, dseg, lane, ngv, nbv, ogv, obv,
                      h, hb_out, writeHb);
          car[0] = car[1] = car[2] = car[3] = 0.f;
          nstart = glob;
          nextn = dseg + 1;
        } else {
#pragma unroll
          for (int t = 0; t < 4; t++) car[t] += rs[t];
        }
        s0 = s1;
      }

      if (!more) break;
      c++; slot = nslot; e = en; A0 = N0; A1 = N1;
    }
  }
  // trailing deg-0 nodes
  for (int n = nextn; n < n1; n++) {
    const float hv0 = h[(size_t)n * 64 + lane];
    node_finish(0.f, 1.f, hv0, n, lane, ngv, nbv, ogv, obv,
                h, hb_out, writeHb);
  }
}

// ------------------------------ pooling (segmented) -------------------------
__global__ void k_pool_seg(const float* __restrict__ h, const int* __restrict__ batch,
                           float* __restrict__ g, float* __restrict__ cnt,
                           int n_nodes, int chunk) {
  const int lane = threadIdx.x & 63;
  const int wid = (blockIdx.x * blockDim.x + threadIdx.x) >> 6;
  const int n0 = wid * chunk;
  if (n0 >= n_nodes) return;
  const int n1 = min(n0 + chunk, n_nodes);
  int cur = batch[n0], c = 0;
  float acc = 0.f;
  for (int n = n0; n < n1; n++) {
    const int b = batch[n];
    if (b != cur) {
      atomicAdd(&g[(size_t)cur * 64 + lane], acc);
      if (lane == 0) atomicAdd(&cnt[cur], (float)c);
      acc = 0.f; c = 0; cur = b;
    }
    acc += h[(size_t)n * 64 + lane];
    c++;
  }
  atomicAdd(&g[(size_t)cur * 64 + lane], acc);
  if (lane == 0) atomicAdd(&cnt[cur], (float)c);
}

// ------------------------------- head --------------------------------------
__global__ void k_head(const float* __restrict__ g, const float* __restrict__ cnt,
                       const float* __restrict__ w1, const float* __restrict__ b1,
                       const float* __restrict__ g1, const float* __restrict__ be1,
                       const float* __restrict__ w2, const float* __restrict__ b2,
                       const float* __restrict__ g2, const float* __restrict__ be2,
                       const float* __restrict__ w3, const float* __restrict__ b3,
                       float* __restrict__ out, int nb_) {
  const int lane = threadIdx.x & 63;
  const int row = (blockIdx.x * blockDim.x + threadIdx.x) >> 6;
  if (row >= nb_) return;
  const float c = fmaxf(cnt[row], 1.0f);
  const float gv = g[row * 64 + lane] / c;
  float a0 = b1[lane], a1 = 0.f, a2 = 0.f, a3 = 0.f;
#pragma unroll
  for (int k = 0; k < 64; k += 4) {
    a0 = fmaf(lane_bcast(gv, k + 0), w1[(k + 0) * 64 + lane], a0);
    a1 = fmaf(lane_bcast(gv, k + 1), w1[(k + 1) * 64 + lane], a1);
    a2 = fmaf(lane_bcast(gv, k + 2), w1[(k + 2) * 64 + lane], a2);
    a3 = fmaf(lane_bcast(gv, k + 3), w1[(k + 3) * 64 + lane], a3);
  }
  float t = (a0 + a1) + (a2 + a3);
  t = fmaxf(ln_apply(t, g1[lane], be1[lane]), 0.0f);

  const int j = lane & 31;
  float c0 = b2[j], c1 = 0.f, c2 = 0.f, c3 = 0.f;
#pragma unroll
  for (int k = 0; k < 64; k += 4) {
    c0 = fmaf(lane_bcast(t, k + 0), w2[(k + 0) * 32 + j], c0);
    c1 = fmaf(lane_bcast(t, k + 1), w2[(k + 1) * 32 + j], c1);
    c2 = fmaf(lane_bcast(t, k + 2), w2[(k + 2) * 32 + j], c2);
    c3 = fmaf(lane_bcast(t, k + 3), w2[(k + 3) * 32 + j], c3);
  }
  float t2 = (c0 + c1) + (c2 + c3);
  t2 = fmaxf(ln_apply(t2, g2[j], be2[j]), 0.0f);
  const float p = t2 * w3[j];
  const float s = wave_sum64(p) * 0.5f;
  if (lane == 0) out[row] = s + b3[0];
}

// ---------------------------------------------------------------------------
extern "C" void kernel_launch(void* const* d_in, const int* in_sizes, int n_in,
                              void* d_out, int out_size, void* d_ws, size_t ws_size,
                              hipStream_t stream) {
  const float* x      = (const float*)d_in[0];
  const float* ea     = (const float*)d_in[1];
  const float* ne_w1  = (const float*)d_in[2];
  const float* ne_b1  = (const float*)d_in[3];
  const float* ne_g1  = (const float*)d_in[4];
  const float* ne_be1 = (const float*)d_in[5];
  const float* ne_w2  = (const float*)d_in[6];
  const float* ne_b2  = (const float*)d_in[7];
  const float* ne_g2  = (const float*)d_in[8];
  const float* ne_be2 = (const float*)d_in[9];
  const float* conv_w = (const float*)d_in[10];
  const float* conv_b = (const float*)d_in[11];
  const float* conv_mg= (const float*)d_in[12];
  const float* conv_mb= (const float*)d_in[13];
  const float* conv_ng= (const float*)d_in[14];
  const float* conv_nb= (const float*)d_in[15];
  const float* out_ng = (const float*)d_in[16];
  const float* out_nb = (const float*)d_in[17];
  const float* m_w1   = (const float*)d_in[18];
  const float* m_b1   = (const float*)d_in[19];
  const float* m_g1   = (const float*)d_in[20];
  const float* m_be1  = (const float*)d_in[21];
  const float* m_w2   = (const float*)d_in[22];
  const float* m_b2   = (const float*)d_in[23];
  const float* m_g2   = (const float*)d_in[24];
  const float* m_be2  = (const float*)d_in[25];
  const float* m_w3   = (const float*)d_in[26];
  const float* m_b3   = (const float*)d_in[27];
  const int*   eidx   = (const int*)d_in[28];
  const int*   batch  = (const int*)d_in[29];
  float* outp = (float*)d_out;

  const int NN = in_sizes[29];
  const int NE = in_sizes[1] / 2;
  const int NB = out_size;

  // workspace
  char* wsb = (char*)d_ws;
  float*  h     = (float*)wsb;                            // NN*64 f32
  ushort* hbA   = (ushort*)(h + (size_t)NN * 64);         // NN*64 bf16
  ushort* hbB   = hbA + (size_t)NN * 64;                  // NN*64 bf16
  int4*   edata = (int4*)(hbB + (size_t)NN * 64);         // NE int4
  ushort* wt    = (ushort*)(edata + NE);                  // 3*64*96 bf16
  float*  gbuf  = (float*)(wt + 3 * 64 * 96);             // NB*64 f32  --+
  float*  cnt   = gbuf + (size_t)NB * 64;                 // NB f32       | zero
  int*    csr   = (int*)(cnt + NB);                       // NN int     --+

  const dim3 blk(256);

  // zero gbuf + cnt + csr in one contiguous memset
  const size_t zbytes = (char*)(csr + NN) - (char*)gbuf;
  hipMemsetAsync(gbuf, 0, zbytes, stream);

  // stage 1: prep(72) | hist
  const int nPrep = (3 * 64 * 96) / 256;              // 72
  const int nHist = (NE + 255) / 256;
  k_init1<<<nPrep + nHist, blk, 0, stream>>>(conv_w, wt, eidx, csr, NE, nPrep);

  k_scan_fast<<<1, 1024, 0, stream>>>(csr, NN);

  // stage 2: XCD-partitioned scatter | embed (R17 proven)
  const int ngroups = 261;                            // 24 scat + 8 emb per group
  const int nOrd = ngroups * 3;
  const int nEmb = ngroups * 8;
  k_combo<<<ngroups * 32, blk, 0, stream>>>(
      eidx, ea, csr, edata, x,
      ne_w1, ne_b1, ne_g1, ne_be1, ne_w2, ne_b2, ne_g2, ne_be2,
      h, hbA, NN, NE, nOrd, nEmb * 4, 8.0f / (float)NN);

  // 3 fused layers (hb ping-pong; h in place, owner-exclusive)
  for (int l = 0; l < 3; l++) {
    const ushort* hin = (l == 1) ? hbB : hbA;
    ushort* hout = (l == 0) ? hbB : hbA;
    k_layer<<<NWV / 4, blk, 0, stream>>>(
        hin, hout, h, edata, csr, wt + (size_t)l * 64 * 96,
        conv_b + l * 64, conv_mg + l * 64, conv_mb + l * 64,
        conv_ng + l * 64, conv_nb + l * 64,
        out_ng + l * 64, out_nb + l * 64, NN, NE, (l < 2) ? 1 : 0);
  }

  {
    const int chunk = 32;
    const int nwaves = (NN + chunk - 1) / chunk;
    const int nblocks = (nwaves * 64 + 255) / 256;
    k_pool_seg<<<nblocks, blk, 0, stream>>>(h, batch, gbuf, cnt, NN, chunk);
  }
  k_head<<<(NB + 3) / 4, blk, 0, stream>>>(gbuf, cnt, m_w1, m_b1, m_g1, m_be1,
                                           m_w2, m_b2, m_g2, m_be2, m_w3, m_b3,
                                           outp, NB);
}